// Round 7
// baseline (689.919 us; speedup 1.0000x reference)
//
#include <hip/hip_runtime.h>

// N=1024, Cin=1024, Cy=256, H=W=128, inter=256 -- all fp32
#define HWDIM 128
#define NPIX  (HWDIM * HWDIM)   // 16384
#define CY    256
#define INTER 256
#define KTAPS 9
#define WEN   (CY * KTAPS)      // 2304
#define NW1   32                // we partial count (phase-1 c-split)
#define NCS   8                 // A channel groups
#define CPG   32                // channels per A group
#define NPART2 256              // softmax partial pairs
#define NRG   4                 // q row-group split
#define GRID  1024              // 4 blocks/CU x 256 CUs: all co-resident

// ---------------------------------------------------------------------------
// Algebra: softmax over axis 1 cancels s_theta (constant along that axis) and
// the uniform phi-bias shift -> x, theta_*, phi_b dead. All 1024 output rows
// identical: z = gamma*(g_b + g_w . q).
//   we[cy,t]    = sum_c wp[c]*phi_w[c,cy,t]
//   A[cg,t,pix] = sum_{cy in cg} we[cy,t]*y[cy,pix]   (tap-first: NO halo)
//   sphi[h,w]   = sum_{cg,t} A[cg,t, shifted(h,w)]    (L2-resident gather)
//   p = softmax(sphi);  q[cy,t] = sum_hw p[h-kh+1,w-kw+1]*y[cy,h,w]
// R6 note: hipLaunchCooperativeKernel silently failed (no-op output) ->
// manual grid barrier: agent-scope release fetch_add + acquire spin.
// Co-residency guaranteed: 1024 blocks = 4/CU, launch_bounds(256,4),
// LDS ~20.5KB <= 40KB/block. Counters zeroed via hipMemsetAsync.
// Harness floor (d_ws re-poison + input restores) ~51us is inside dur_us.
// ---------------------------------------------------------------------------

__device__ __forceinline__ float wave_red_sum(float v) {
    #pragma unroll
    for (int s = 32; s > 0; s >>= 1) v += __shfl_down(v, s, 64);
    return v;
}
__device__ __forceinline__ float wave_red_max(float v) {
    #pragma unroll
    for (int s = 32; s > 0; s >>= 1) v = fmaxf(v, __shfl_down(v, s, 64));
    return v;
}

// Grid-wide barrier: one fresh counter per use. Release-add + acquire-spin at
// agent scope -> compiler emits the L2 writeback/invalidate needed across XCDs.
__device__ __forceinline__ void grid_bar(int* cnt) {
    __syncthreads();
    if (threadIdx.x == 0) {
        __hip_atomic_fetch_add(cnt, 1, __ATOMIC_RELEASE,
                               __HIP_MEMORY_SCOPE_AGENT);
        while (__hip_atomic_load(cnt, __ATOMIC_ACQUIRE,
                                 __HIP_MEMORY_SCOPE_AGENT) < GRID)
            __builtin_amdgcn_s_sleep(2);
    }
    __syncthreads();
}

__global__ __launch_bounds__(256, 4)
void fused_all(const float* __restrict__ y,
               const float* __restrict__ g_w,
               const float* __restrict__ g_b,
               const float* __restrict__ phi_w,
               const float* __restrict__ concat_w,
               const float* __restrict__ gamma,
               float* __restrict__ out, int out_size,
               int* __restrict__ bar,          // 5 counters, stride 16
               float* __restrict__ we_part,
               float* __restrict__ A,
               float* __restrict__ sphi,
               float* __restrict__ partials,
               float* __restrict__ q_part,
               float* __restrict__ row_part) {
    const int b = blockIdx.x, t = threadIdx.x;
    const int wid = t >> 6, lane = t & 63;

    __shared__ float sp[34 * 130];        // 17.7 KB p tile (phase 4)
    __shared__ float swe[CPG * KTAPS];    // phase 2
    __shared__ float sred[256];           // phases 3/6
    __shared__ float s4a[4], s4b[4];
    __shared__ float sq4[4][KTAPS];

    // ---- P1: we_part[cg][o] = sum_{8 c} wp[c]*phi_w[c,o]  (288 blocks) ----
    if (b < 288) {
        int cgp = b / 9, og = b - cgp * 9;
        int o = og * 256 + t;
        const float* pw = phi_w + o;
        float acc = 0.f;
        #pragma unroll
        for (int j = 0; j < 8; ++j) {
            int c = cgp * 8 + j;
            acc = fmaf(concat_w[INTER + c], pw[c * WEN], acc);
        }
        we_part[cgp * WEN + o] = acc;
    }
    grid_bar(bar + 0 * 16);

    // ---- P2: A[cg][k][pix] = sum_{ch in cg} we[.]*y[.]  (512 blocks) ----
    if (b < 512) {
        int pg = b & 63, cgA = b >> 6;
        for (int i = t; i < CPG * KTAPS; i += 256) {
            float s = 0.f;
            #pragma unroll
            for (int p = 0; p < NW1; ++p)
                s += we_part[p * WEN + cgA * CPG * KTAPS + i];
            swe[i] = s;
        }
        __syncthreads();

        int pix = pg * 256 + t;
        float acc[KTAPS];
        #pragma unroll
        for (int k = 0; k < KTAPS; ++k) acc[k] = 0.f;
        const float* yp = y + (size_t)cgA * CPG * NPIX + pix;
        #pragma unroll 4
        for (int ch = 0; ch < CPG; ++ch) {
            float yv = yp[ch * NPIX];
            const float* wk = swe + ch * KTAPS;   // wave-uniform broadcast
            #pragma unroll
            for (int k = 0; k < KTAPS; ++k)
                acc[k] = fmaf(wk[k], yv, acc[k]);
        }
        #pragma unroll
        for (int k = 0; k < KTAPS; ++k)
            A[(size_t)(cgA * KTAPS + k) * NPIX + pix] = acc[k];
    }
    grid_bar(bar + 1 * 16);

    // ---- P3: sphi + per-block softmax partials (256 blocks, 64 pix each) --
    if (b < NPART2) {
        int tg = t >> 6, pl = t & 63;
        int pix = b * 64 + pl;
        int h = pix >> 7, w = pix & 127;

        int idx[KTAPS]; bool val[KTAPS];
        #pragma unroll
        for (int kh = 0; kh < 3; ++kh)
            #pragma unroll
            for (int kw = 0; kw < 3; ++kw) {
                int hh = h + kh - 1, ww = w + kw - 1;
                int k = kh * 3 + kw;
                val[k] = ((unsigned)hh < HWDIM) & ((unsigned)ww < HWDIM);
                idx[k] = hh * HWDIM + ww;
            }

        float acc = 0.f;
        #pragma unroll
        for (int cc = 0; cc < 2; ++cc) {
            const float* Ab = A + (size_t)(tg * 2 + cc) * KTAPS * NPIX;
            #pragma unroll
            for (int k = 0; k < KTAPS; ++k)
                if (val[k]) acc += Ab[(size_t)k * NPIX + idx[k]];
        }
        sred[t] = acc;
        __syncthreads();

        if (t < 64) {
            float v = sred[t] + sred[t + 64] + sred[t + 128] + sred[t + 192];
            sphi[b * 64 + t] = v;
            float m = wave_red_max(v);
            float M = __shfl(m, 0, 64);
            float e = expf(v - M);
            float s = wave_red_sum(e);
            if (t == 0) {
                partials[2 * b]     = M;
                partials[2 * b + 1] = s;
            }
        }
    }
    grid_bar(bar + 2 * 16);

    // ---- P4: q_part over a 32-row slice (all 1024 blocks) ----
    {
        int cy = b & 255, rg = b >> 8;

        // merge 256 softmax partial pairs -> M, invS
        float m = partials[2 * t], s = partials[2 * t + 1];
        float wm = wave_red_max(m);
        if (lane == 0) s4a[wid] = wm;
        __syncthreads();
        float M = fmaxf(fmaxf(s4a[0], s4a[1]), fmaxf(s4a[2], s4a[3]));
        float sv = s * expf(m - M);
        float wsum = wave_red_sum(sv);
        if (lane == 0) s4b[wid] = wsum;
        __syncthreads();
        float invS = 1.f / (s4b[0] + s4b[1] + s4b[2] + s4b[3]);

        // stage p tile: sp[r][col] = p[rg*32 + r - 1][col - 1], zero-padded
        for (int i = t; i < 34 * 130; i += 256) {
            int r = i / 130, col = i - r * 130;
            int gr = rg * 32 + r - 1, gc = col - 1;
            float v = 0.f;
            if ((unsigned)gr < HWDIM && (unsigned)gc < HWDIM)
                v = expf(sphi[gr * HWDIM + gc] - M) * invS;
            sp[i] = v;
        }
        __syncthreads();

        const float* yc = y + (size_t)cy * NPIX;
        float acc[KTAPS];
        #pragma unroll
        for (int k = 0; k < KTAPS; ++k) acc[k] = 0.f;
        int c = t & 127, vg = t >> 7;

        for (int j = 0; j < 4; ++j) {
            int lr0 = vg * 4 + j * 8;     // local row base (0..28)
            float pv[6][3];
            #pragma unroll
            for (int u = 0; u < 6; ++u)
                #pragma unroll
                for (int v = 0; v < 3; ++v)
                    pv[u][v] = sp[(lr0 + u) * 130 + c + v];
            #pragma unroll
            for (int dr = 0; dr < 4; ++dr) {
                float yv = yc[(rg * 32 + lr0 + dr) * HWDIM + c];
                #pragma unroll
                for (int kh = 0; kh < 3; ++kh)
                    #pragma unroll
                    for (int kw = 0; kw < 3; ++kw)
                        acc[kh * 3 + kw] = fmaf(pv[dr + 2 - kh][2 - kw], yv,
                                                acc[kh * 3 + kw]);
            }
        }

        #pragma unroll
        for (int k = 0; k < KTAPS; ++k) {
            float v = wave_red_sum(acc[k]);
            if (lane == 0) sq4[wid][k] = v;
        }
        __syncthreads();
        if (t < KTAPS)
            q_part[rg * WEN + cy * KTAPS + t] =
                sq4[0][t] + sq4[1][t] + sq4[2][t] + sq4[3][t];
    }
    grid_bar(bar + 3 * 16);

    // ---- P5: row_part[half][c] = g_w[c, half] . q   (512 blocks) ----
    if (b < 512) {
        int c = b & 255, half = b >> 8;
        int base = half * (WEN / 2);      // 1152
        const float* gw = g_w + (size_t)c * WEN;
        float acc = 0.f;
        #pragma unroll
        for (int j = 0; j < 5; ++j) {
            int o = base + j * 256 + t;
            if (o < base + WEN / 2) {
                float qv = q_part[o] + q_part[WEN + o] +
                           q_part[2 * WEN + o] + q_part[3 * WEN + o];
                acc = fmaf(gw[o], qv, acc);
            }
        }
        float v = wave_red_sum(acc);
        if (lane == 0) s4a[wid] = v;
        __syncthreads();
        if (t == 0)
            row_part[half * 256 + c] = s4a[0] + s4a[1] + s4a[2] + s4a[3];
    }
    grid_bar(bar + 4 * 16);

    // ---- P6: out[i*256+c] = gamma*(g_b[c] + rp0[c] + rp1[c])  (all) ----
    {
        float rv = gamma[0] * (g_b[t] + row_part[t] + row_part[256 + t]);
        sred[t] = rv;
        __syncthreads();
        int gid = b * 256 + t;
        if (gid < out_size) out[gid] = sred[t];
    }
}

extern "C" void kernel_launch(void* const* d_in, const int* in_sizes, int n_in,
                              void* d_out, int out_size, void* d_ws, size_t ws_size,
                              hipStream_t stream) {
    // inputs: x, y, g_w, g_b, phi_w, phi_b, theta_w, theta_b, concat_w, gamma
    const float* y        = (const float*)d_in[1];
    const float* g_w      = (const float*)d_in[2];
    const float* g_b      = (const float*)d_in[3];
    const float* phi_w    = (const float*)d_in[4];
    const float* concat_w = (const float*)d_in[8];
    const float* gamma    = (const float*)d_in[9];
    float* out = (float*)d_out;

    int*   bar      = (int*)d_ws;                    // 5 counters, stride 16
    float* ws       = (float*)d_ws + 128;
    float* we_part  = ws;                            // 32*2304   = 73728
    float* A        = we_part + NW1 * WEN;           // 8*9*16384 = 1179648
    float* sphi     = A + (size_t)NCS * KTAPS * NPIX;// 16384
    float* partials = sphi + NPIX;                   // 512
    float* q_part   = partials + 2 * NPART2;         // 4*2304
    float* row_part = q_part + NRG * WEN;            // 512
    (void)in_sizes; (void)n_in; (void)ws_size;

    hipMemsetAsync(bar, 0, 128 * sizeof(int), stream);
    hipLaunchKernelGGL(fused_all, dim3(GRID), dim3(256), 0, stream,
                       y, g_w, g_b, phi_w, concat_w, gamma, out, out_size,
                       bar, we_part, A, sphi, partials, q_part, row_part);
}

// Round 8
// 191.838 us; speedup vs baseline: 3.5964x; 3.5964x over previous
//
#include <hip/hip_runtime.h>

// N=1024, Cin=1024, Cy=256, H=W=128, inter=256 -- all fp32
#define HWDIM 128
#define NPIX  (HWDIM * HWDIM)   // 16384
#define CY    256
#define INTER 256
#define KTAPS 9
#define WEN   (CY * KTAPS)      // 2304
#define NW1   32                // we partial count (K1 c-split)
#define NCS   8                 // A channel groups
#define CPG   32                // channels per A group
#define NRG   64                // q row groups (2 rows each)
#define RPG   2                 // rows per group
#define NCYG  8                 // K3 channel groups (32 ch each)

// ---------------------------------------------------------------------------
// Algebra: softmax over axis 1 cancels s_theta (constant along that axis) and
// the uniform phi-bias shift -> x, theta_*, phi_b dead. All 1024 output rows
// identical: z = gamma*(g_b + g_w . q).
//   we[cy,t]    = sum_c wp[c]*phi_w[c,cy,t]
//   A[cg,t,pix] = sum_{cy in cg} we[cy,t]*y[cy,pix]   (tap-first: NO halo)
//   sphi[h,w]   = sum_{cg,t} A[cg,t, shifted(h,w)]
//   p = softmax(sphi);  q[cy,t] = sum_hw p[h-kh+1,w-kw+1]*y[cy,h,w]
// R7 lesson: intra-kernel grid barriers cost ~120us each on multi-XCD gfx950
// (agent-scope release/acquire = L2 writeback/invalidate storms). Stay with
// kernel-boundary sync; cut kernels 6->4 via flash-style local-max softmax:
// K3 block (rg,cyg) computes its own sphi tile from A, uses LOCAL max M_rg,
// emits unnormalized q_part[rg] + (M_rg,S_rg); K4 merges exactly:
//   q = sum_rg exp(M_rg-M)/S * q_part[rg],  S = sum_rg exp(M_rg-M)*S_rg.
// M_rg is bitwise-identical across the 8 cyg blocks of one rg (same inputs,
// same op order), so a single MS[rg] entry is valid for all of them.
// Harness floor (d_ws re-poison ~43us + input restores ~8us) is inside dur_us.
// ---------------------------------------------------------------------------

__device__ __forceinline__ float wave_red_sum(float v) {
    #pragma unroll
    for (int s = 32; s > 0; s >>= 1) v += __shfl_down(v, s, 64);
    return v;
}
__device__ __forceinline__ float wave_red_max(float v) {
    #pragma unroll
    for (int s = 32; s > 0; s >>= 1) v = fmaxf(v, __shfl_down(v, s, 64));
    return v;
}

// K1: we_part[cg][o] = sum_{8 c} wp[c]*phi_w[c,o]   (288 = 32 cg x 9 og)
__global__ __launch_bounds__(256)
void k1_wepart(const float* __restrict__ phi_w,
               const float* __restrict__ concat_w,
               float* __restrict__ we_part) {
    int b = blockIdx.x, t = threadIdx.x;
    int cg = b / 9, og = b - cg * 9;
    int o = og * 256 + t;
    const float* pw = phi_w + o;
    float acc = 0.f;
    #pragma unroll
    for (int j = 0; j < 8; ++j) {
        int c = cg * 8 + j;
        acc = fmaf(concat_w[INTER + c], pw[c * WEN], acc);
    }
    we_part[cg * WEN + o] = acc;
}

// K2: A[cg][k][pix] = sum_{ch in cg} we[.]*y[.]   (512 = 8 cg x 64 pg)
__global__ __launch_bounds__(256)
void k2_taps(const float* __restrict__ y,
             const float* __restrict__ we_part,
             float* __restrict__ A) {
    __shared__ float swe[CPG * KTAPS];
    int t = threadIdx.x;
    int pg = blockIdx.x & 63, cg = blockIdx.x >> 6;

    for (int i = t; i < CPG * KTAPS; i += 256) {
        float s = 0.f;
        #pragma unroll
        for (int p = 0; p < NW1; ++p)
            s += we_part[p * WEN + cg * CPG * KTAPS + i];
        swe[i] = s;
    }
    __syncthreads();

    int pix = pg * 256 + t;
    float acc[KTAPS];
    #pragma unroll
    for (int k = 0; k < KTAPS; ++k) acc[k] = 0.f;
    const float* yp = y + (size_t)cg * CPG * NPIX + pix;
    #pragma unroll 4
    for (int ch = 0; ch < CPG; ++ch) {
        float yv = yp[ch * NPIX];
        const float* wk = swe + ch * KTAPS;     // wave-uniform broadcast
        #pragma unroll
        for (int k = 0; k < KTAPS; ++k)
            acc[k] = fmaf(wk[k], yv, acc[k]);
    }
    #pragma unroll
    for (int k = 0; k < KTAPS; ++k)
        A[(size_t)(cg * KTAPS + k) * NPIX + pix] = acc[k];
}

// K3: fused sphi-tile + local softmax + q.  grid 512 = 64 rg x 8 cyg.
// Block (rg,cyg): rows rg*2..rg*2+1, channels cyg*32..+31.
__global__ __launch_bounds__(256)
void k3_q(const float* __restrict__ y,
          const float* __restrict__ A,
          float* __restrict__ q_part,
          float* __restrict__ MS) {
    __shared__ float ssph[4 * 130];     // sphi tile rows R0-1..R0+2, cols -1..128
    __shared__ float s4[4];
    int b = blockIdx.x;
    int rg = b >> 3, cyg = b & 7;
    int t = threadIdx.x;
    int wid = t >> 6, lane = t & 63;
    const int R0 = rg * RPG;

    // 1. sphi tile from A (out-of-image -> -inf so exp gives 0)
    for (int i = t; i < 4 * 130; i += 256) {
        int r = i / 130, col = i - r * 130;
        int h = R0 + r - 1, w = col - 1;
        float v;
        if ((unsigned)h < (unsigned)HWDIM && (unsigned)w < (unsigned)HWDIM) {
            v = 0.f;
            #pragma unroll
            for (int kh = 0; kh < 3; ++kh) {
                int hh = h + kh - 1;
                if ((unsigned)hh >= (unsigned)HWDIM) continue;
                #pragma unroll
                for (int kw = 0; kw < 3; ++kw) {
                    int ww = w + kw - 1;
                    if ((unsigned)ww >= (unsigned)HWDIM) continue;
                    int k = kh * 3 + kw;
                    int idx = hh * HWDIM + ww;
                    #pragma unroll
                    for (int cg = 0; cg < NCS; ++cg)
                        v += A[(size_t)(cg * KTAPS + k) * NPIX + idx];
                }
            }
        } else {
            v = -INFINITY;
        }
        ssph[i] = v;
    }
    __syncthreads();

    // 2. local max over tile
    float m = -INFINITY;
    for (int i = t; i < 4 * 130; i += 256) m = fmaxf(m, ssph[i]);
    float wm = wave_red_max(m);
    if (lane == 0) s4[wid] = wm;
    __syncthreads();
    float M = fmaxf(fmaxf(s4[0], s4[1]), fmaxf(s4[2], s4[3]));

    // 3. unnormalized p in place (exp(-inf - M) == 0)
    for (int i = t; i < 4 * 130; i += 256) ssph[i] = expf(ssph[i] - M);
    __syncthreads();

    // 4. S over OWNED region only (tile rows 1..2, cols 1..128): 256 entries
    {
        int r = 1 + (t >> 7), col = 1 + (t & 127);
        float sv = ssph[r * 130 + col];
        float ws = wave_red_sum(sv);
        if (lane == 0) s4[wid] = ws;
        __syncthreads();
        if (cyg == 0 && t == 0) {
            MS[rg * 2]     = M;
            MS[rg * 2 + 1] = s4[0] + s4[1] + s4[2] + s4[3];
        }
    }

    // 5. q: wave owns 8 channels; lane owns cols 2*lane, 2*lane+1, both rows.
    const int c2 = lane * 2;
    float pv[4][4];
    #pragma unroll
    for (int r = 0; r < 4; ++r)
        #pragma unroll
        for (int j = 0; j < 4; ++j)
            pv[r][j] = ssph[r * 130 + c2 + j];

    const int base_cy = cyg * 32 + wid * 8;
    for (int ch = 0; ch < 8; ++ch) {
        const float* yc = y + (size_t)(base_cy + ch) * NPIX;
        float2 y0 = ((const float2*)(yc + (size_t)R0 * HWDIM))[lane];
        float2 y1 = ((const float2*)(yc + (size_t)(R0 + 1) * HWDIM))[lane];
        float acc[KTAPS];
        #pragma unroll
        for (int kh = 0; kh < 3; ++kh)
            #pragma unroll
            for (int kw = 0; kw < 3; ++kw) {
                int k = kh * 3 + kw;
                // y pixel (row r, col c2+cc) pairs with p tile
                // [r + 2 - kh][c2 + cc + 2 - kw]
                acc[k] = pv[2 - kh][2 - kw] * y0.x + pv[2 - kh][3 - kw] * y0.y
                       + pv[3 - kh][2 - kw] * y1.x + pv[3 - kh][3 - kw] * y1.y;
            }
        #pragma unroll
        for (int k = 0; k < KTAPS; ++k) {
            float v = wave_red_sum(acc[k]);
            if (lane == 0)
                q_part[(size_t)rg * WEN + (base_cy + ch) * KTAPS + k] = v;
        }
    }
}

// K4: merge q partials (flash rescale), 256 dots, broadcast. 16 blocks x 256.
__global__ __launch_bounds__(256)
void k4_out(const float* __restrict__ g_w,
            const float* __restrict__ g_b,
            const float* __restrict__ gamma,
            const float* __restrict__ q_part,
            const float* __restrict__ MS,
            float* __restrict__ out, int out_size) {
    __shared__ float sms[2 * NRG];      // 128
    __shared__ float sfac[NRG];
    __shared__ float sq[WEN];
    __shared__ float srow[16];
    int t = threadIdx.x, b = blockIdx.x;

    if (t < 2 * NRG) sms[t] = MS[t];
    __syncthreads();

    // global M, S (redundant per-thread; 64 iterations, trivial)
    float M = -INFINITY;
    #pragma unroll 8
    for (int i = 0; i < NRG; ++i) M = fmaxf(M, sms[2 * i]);
    float S = 0.f;
    #pragma unroll 8
    for (int i = 0; i < NRG; ++i) S += expf(sms[2 * i] - M) * sms[2 * i + 1];
    if (t < NRG) sfac[t] = expf(sms[2 * t] - M) / S;
    __syncthreads();

    // merged q into LDS
    for (int o = t; o < WEN; o += 256) {
        float v = 0.f;
        #pragma unroll 8
        for (int rg = 0; rg < NRG; ++rg)
            v = fmaf(sfac[rg], q_part[(size_t)rg * WEN + o], v);
        sq[o] = v;
    }
    __syncthreads();

    // 16 dots: 16 threads per out-channel
    int cl = t >> 4, sub = t & 15;
    int c = b * 16 + cl;
    const float* gw = g_w + (size_t)c * WEN;
    float acc = 0.f;
    for (int j = sub; j < WEN; j += 16) acc = fmaf(gw[j], sq[j], acc);
    #pragma unroll
    for (int s = 8; s > 0; s >>= 1) acc += __shfl_down(acc, s, 16);
    if (sub == 0) srow[cl] = gamma[0] * (g_b[c] + acc);
    __syncthreads();

    // broadcast: block owns 16 columns; 16 rows per pass, 64B per 16 lanes
    int c0 = b * 16;
    for (int pass = 0; pass < 64; ++pass) {
        int r = pass * 16 + cl;
        int gid = r * 256 + c0 + sub;
        if (gid < out_size) out[gid] = srow[sub];
    }
}

extern "C" void kernel_launch(void* const* d_in, const int* in_sizes, int n_in,
                              void* d_out, int out_size, void* d_ws, size_t ws_size,
                              hipStream_t stream) {
    // inputs: x, y, g_w, g_b, phi_w, phi_b, theta_w, theta_b, concat_w, gamma
    const float* y        = (const float*)d_in[1];
    const float* g_w      = (const float*)d_in[2];
    const float* g_b      = (const float*)d_in[3];
    const float* phi_w    = (const float*)d_in[4];
    const float* concat_w = (const float*)d_in[8];
    const float* gamma    = (const float*)d_in[9];
    float* out = (float*)d_out;

    float* ws       = (float*)d_ws;
    float* we_part  = ws;                              // 32*2304   = 73728
    float* A        = we_part + NW1 * WEN;             // 8*9*16384 = 1179648
    float* q_part   = A + (size_t)NCS * KTAPS * NPIX;  // 64*2304   = 147456
    float* MS       = q_part + (size_t)NRG * WEN;      // 128
    (void)in_sizes; (void)n_in; (void)ws_size;

    hipLaunchKernelGGL(k1_wepart, dim3(288), dim3(256), 0, stream,
                       phi_w, concat_w, we_part);
    hipLaunchKernelGGL(k2_taps,   dim3(512), dim3(256), 0, stream,
                       y, we_part, A);
    hipLaunchKernelGGL(k3_q,      dim3(512), dim3(256), 0, stream,
                       y, A, q_part, MS);
    hipLaunchKernelGGL(k4_out,    dim3(16),  dim3(256), 0, stream,
                       g_w, g_b, gamma, q_part, MS, out, out_size);
}

// Round 9
// 164.287 us; speedup vs baseline: 4.1995x; 1.1677x over previous
//
#include <hip/hip_runtime.h>

// N=1024, Cin=1024, Cy=256, H=W=128, inter=256 -- all fp32
#define HWDIM 128
#define NPIX  (HWDIM * HWDIM)   // 16384
#define CY    256
#define INTER 256
#define KTAPS 9
#define WEN   (CY * KTAPS)      // 2304
#define NW1   32                // we partial count (K1 c-split)
#define NCS   8                 // A channel groups
#define CPG   32                // channels per A group
#define NRG   64                // q row groups (2 rows each)
#define RPG   2                 // rows per group

// ---------------------------------------------------------------------------
// Algebra: softmax over axis 1 cancels s_theta (constant along that axis) and
// the uniform phi-bias shift -> x, theta_*, phi_b dead. All 1024 output rows
// identical: z = gamma*(g_b + g_w . q).
//   we[cy,t]    = sum_c wp[c]*phi_w[c,cy,t]
//   A[cg,t,pix] = sum_{cy in cg} we[cy,t]*y[cy,pix]   (tap-first: NO halo)
//   sphi[h,w]   = sum_{cg,t} A[cg,t, shifted(h,w)]
//   p = softmax(sphi);  q[cy,t] = sum_hw p[h-kh+1,w-kw+1]*y[cy,h,w]
// K3 uses flash-style LOCAL max per row-group (M_rg bitwise-identical across
// the 8 cyg blocks of an rg); K4 merges exactly:
//   q = sum_rg exp(M_rg-M)/S * q_part[rg],  S = sum_rg exp(M_rg-M)*S_rg.
// R7 lesson: intra-kernel grid barriers ~120us each on multi-XCD gfx950 ->
// kernel-boundary sync only.
// R8 lesson: k4 @16 blocks was latency-bound (85us, 0.6% occupancy, 576
// scattered dependent q_part loads/thread at ~900cyc). Fix: 256 blocks (one
// per out-channel), fused merge+dot per block, column-wise broadcast.
// Harness floor (d_ws re-poison ~43us + input restores ~8us) inside dur_us.
// ---------------------------------------------------------------------------

__device__ __forceinline__ float wave_red_sum(float v) {
    #pragma unroll
    for (int s = 32; s > 0; s >>= 1) v += __shfl_down(v, s, 64);
    return v;
}
__device__ __forceinline__ float wave_red_max(float v) {
    #pragma unroll
    for (int s = 32; s > 0; s >>= 1) v = fmaxf(v, __shfl_down(v, s, 64));
    return v;
}

// K1: we_part[cg][o] = sum_{8 c} wp[c]*phi_w[c,o]   (288 = 32 cg x 9 og)
__global__ __launch_bounds__(256)
void k1_wepart(const float* __restrict__ phi_w,
               const float* __restrict__ concat_w,
               float* __restrict__ we_part) {
    int b = blockIdx.x, t = threadIdx.x;
    int cg = b / 9, og = b - cg * 9;
    int o = og * 256 + t;
    const float* pw = phi_w + o;
    float acc = 0.f;
    #pragma unroll
    for (int j = 0; j < 8; ++j) {
        int c = cg * 8 + j;
        acc = fmaf(concat_w[INTER + c], pw[c * WEN], acc);
    }
    we_part[cg * WEN + o] = acc;
}

// K2: A[cg][k][pix] = sum_{ch in cg} we[.]*y[.]   (512 = 8 cg x 64 pg)
__global__ __launch_bounds__(256)
void k2_taps(const float* __restrict__ y,
             const float* __restrict__ we_part,
             float* __restrict__ A) {
    __shared__ float swe[CPG * KTAPS];
    int t = threadIdx.x;
    int pg = blockIdx.x & 63, cg = blockIdx.x >> 6;

    for (int i = t; i < CPG * KTAPS; i += 256) {
        float s = 0.f;
        #pragma unroll
        for (int p = 0; p < NW1; ++p)
            s += we_part[p * WEN + cg * CPG * KTAPS + i];
        swe[i] = s;
    }
    __syncthreads();

    int pix = pg * 256 + t;
    float acc[KTAPS];
    #pragma unroll
    for (int k = 0; k < KTAPS; ++k) acc[k] = 0.f;
    const float* yp = y + (size_t)cg * CPG * NPIX + pix;
    #pragma unroll 4
    for (int ch = 0; ch < CPG; ++ch) {
        float yv = yp[ch * NPIX];
        const float* wk = swe + ch * KTAPS;     // wave-uniform broadcast
        #pragma unroll
        for (int k = 0; k < KTAPS; ++k)
            acc[k] = fmaf(wk[k], yv, acc[k]);
    }
    #pragma unroll
    for (int k = 0; k < KTAPS; ++k)
        A[(size_t)(cg * KTAPS + k) * NPIX + pix] = acc[k];
}

// K3: fused sphi-tile + local softmax + q.  grid 512 = 64 rg x 8 cyg.
// Block (rg,cyg): rows rg*2..rg*2+1, channels cyg*32..+31.
__global__ __launch_bounds__(256)
void k3_q(const float* __restrict__ y,
          const float* __restrict__ A,
          float* __restrict__ q_part,
          float* __restrict__ MS) {
    __shared__ float ssph[4 * 130];     // sphi tile rows R0-1..R0+2, cols -1..128
    __shared__ float s4[4];
    int b = blockIdx.x;
    int rg = b >> 3, cyg = b & 7;
    int t = threadIdx.x;
    int wid = t >> 6, lane = t & 63;
    const int R0 = rg * RPG;

    // 1. sphi tile from A (out-of-image -> -inf so exp gives 0)
    for (int i = t; i < 4 * 130; i += 256) {
        int r = i / 130, col = i - r * 130;
        int h = R0 + r - 1, w = col - 1;
        float v;
        if ((unsigned)h < (unsigned)HWDIM && (unsigned)w < (unsigned)HWDIM) {
            v = 0.f;
            #pragma unroll
            for (int kh = 0; kh < 3; ++kh) {
                int hh = h + kh - 1;
                if ((unsigned)hh >= (unsigned)HWDIM) continue;
                #pragma unroll
                for (int kw = 0; kw < 3; ++kw) {
                    int ww = w + kw - 1;
                    if ((unsigned)ww >= (unsigned)HWDIM) continue;
                    int k = kh * 3 + kw;
                    int idx = hh * HWDIM + ww;
                    #pragma unroll
                    for (int cg = 0; cg < NCS; ++cg)
                        v += A[(size_t)(cg * KTAPS + k) * NPIX + idx];
                }
            }
        } else {
            v = -INFINITY;
        }
        ssph[i] = v;
    }
    __syncthreads();

    // 2. local max over tile
    float m = -INFINITY;
    for (int i = t; i < 4 * 130; i += 256) m = fmaxf(m, ssph[i]);
    float wm = wave_red_max(m);
    if (lane == 0) s4[wid] = wm;
    __syncthreads();
    float M = fmaxf(fmaxf(s4[0], s4[1]), fmaxf(s4[2], s4[3]));

    // 3. unnormalized p in place (exp(-inf - M) == 0)
    for (int i = t; i < 4 * 130; i += 256) ssph[i] = expf(ssph[i] - M);
    __syncthreads();

    // 4. S over OWNED region only (tile rows 1..2, cols 1..128)
    {
        int r = 1 + (t >> 7), col = 1 + (t & 127);
        float sv = ssph[r * 130 + col];
        float ws = wave_red_sum(sv);
        if (lane == 0) s4[wid] = ws;
        __syncthreads();
        if (cyg == 0 && t == 0) {
            MS[rg * 2]     = M;
            MS[rg * 2 + 1] = s4[0] + s4[1] + s4[2] + s4[3];
        }
    }

    // 5. q: wave owns 8 channels; lane owns cols 2*lane, 2*lane+1, both rows.
    const int c2 = lane * 2;
    float pv[4][4];
    #pragma unroll
    for (int r = 0; r < 4; ++r)
        #pragma unroll
        for (int j = 0; j < 4; ++j)
            pv[r][j] = ssph[r * 130 + c2 + j];

    const int base_cy = cyg * 32 + wid * 8;
    for (int ch = 0; ch < 8; ++ch) {
        const float* yc = y + (size_t)(base_cy + ch) * NPIX;
        float2 y0 = ((const float2*)(yc + (size_t)R0 * HWDIM))[lane];
        float2 y1 = ((const float2*)(yc + (size_t)(R0 + 1) * HWDIM))[lane];
        float acc[KTAPS];
        #pragma unroll
        for (int kh = 0; kh < 3; ++kh)
            #pragma unroll
            for (int kw = 0; kw < 3; ++kw) {
                int k = kh * 3 + kw;
                acc[k] = pv[2 - kh][2 - kw] * y0.x + pv[2 - kh][3 - kw] * y0.y
                       + pv[3 - kh][2 - kw] * y1.x + pv[3 - kh][3 - kw] * y1.y;
            }
        #pragma unroll
        for (int k = 0; k < KTAPS; ++k) {
            float v = wave_red_sum(acc[k]);
            if (lane == 0)
                q_part[(size_t)rg * WEN + (base_cy + ch) * KTAPS + k] = v;
        }
    }
}

// K4: one block per out-channel c. Fused flash-merge + dot + column bcast.
// grid 256 x 256.
__global__ __launch_bounds__(256)
void k4_out(const float* __restrict__ g_w,
            const float* __restrict__ g_b,
            const float* __restrict__ gamma,
            const float* __restrict__ q_part,
            const float* __restrict__ MS,
            float* __restrict__ out, int out_size) {
    __shared__ float sms[2 * NRG];      // 128
    __shared__ float sfac[NRG];
    __shared__ float s4[4];
    __shared__ float srv;
    int t = threadIdx.x, c = blockIdx.x;
    int wid = t >> 6, lane = t & 63;

    if (t < 2 * NRG) sms[t] = MS[t];
    __syncthreads();

    // global M,S (redundant per-thread, 64 iters, trivial)
    float M = -INFINITY;
    #pragma unroll 8
    for (int i = 0; i < NRG; ++i) M = fmaxf(M, sms[2 * i]);
    float S = 0.f;
    #pragma unroll 8
    for (int i = 0; i < NRG; ++i) S += expf(sms[2 * i] - M) * sms[2 * i + 1];
    if (t < NRG) sfac[t] = expf(sms[2 * t] - M) / S;
    __syncthreads();

    // fused merge+dot: thread t owns o = t, t+256, ... (9 values)
    const float* gw = g_w + (size_t)c * WEN;
    float dot = 0.f;
    #pragma unroll
    for (int j = 0; j < 9; ++j) {
        int o = j * 256 + t;
        float v = 0.f;
        #pragma unroll 8
        for (int rg = 0; rg < NRG; ++rg)
            v = fmaf(sfac[rg], q_part[(size_t)rg * WEN + o], v);
        dot = fmaf(gw[o], v, dot);
    }
    float wsum = wave_red_sum(dot);
    if (lane == 0) s4[wid] = wsum;
    __syncthreads();
    if (t == 0)
        srv = gamma[0] * (g_b[c] + s4[0] + s4[1] + s4[2] + s4[3]);
    __syncthreads();
    float rv = srv;

    // column broadcast: out[r*256 + c] for r = t, t+256, t+512, t+768
    #pragma unroll
    for (int i = 0; i < 4; ++i) {
        int r = i * 256 + t;
        int gid = r * 256 + c;
        if (gid < out_size) out[gid] = rv;
    }
}

extern "C" void kernel_launch(void* const* d_in, const int* in_sizes, int n_in,
                              void* d_out, int out_size, void* d_ws, size_t ws_size,
                              hipStream_t stream) {
    // inputs: x, y, g_w, g_b, phi_w, phi_b, theta_w, theta_b, concat_w, gamma
    const float* y        = (const float*)d_in[1];
    const float* g_w      = (const float*)d_in[2];
    const float* g_b      = (const float*)d_in[3];
    const float* phi_w    = (const float*)d_in[4];
    const float* concat_w = (const float*)d_in[8];
    const float* gamma    = (const float*)d_in[9];
    float* out = (float*)d_out;

    float* ws       = (float*)d_ws;
    float* we_part  = ws;                              // 32*2304   = 73728
    float* A        = we_part + NW1 * WEN;             // 8*9*16384 = 1179648
    float* q_part   = A + (size_t)NCS * KTAPS * NPIX;  // 64*2304   = 147456
    float* MS       = q_part + (size_t)NRG * WEN;      // 128
    (void)in_sizes; (void)n_in; (void)ws_size;

    hipLaunchKernelGGL(k1_wepart, dim3(288), dim3(256), 0, stream,
                       phi_w, concat_w, we_part);
    hipLaunchKernelGGL(k2_taps,   dim3(512), dim3(256), 0, stream,
                       y, we_part, A);
    hipLaunchKernelGGL(k3_q,      dim3(512), dim3(256), 0, stream,
                       y, A, q_part, MS);
    hipLaunchKernelGGL(k4_out,    dim3(256), dim3(256), 0, stream,
                       g_w, g_b, gamma, q_part, MS, out, out_size);
}

// Round 10
// 120.161 us; speedup vs baseline: 5.7416x; 1.3672x over previous
//
#include <hip/hip_runtime.h>

// N=1024, Cin=1024, Cy=256, H=W=128, inter=256 -- all fp32
#define HWDIM 128
#define NPIX  (HWDIM * HWDIM)   // 16384
#define CY    256
#define INTER 256
#define KTAPS 9
#define WEN   (CY * KTAPS)      // 2304
#define NW1   32                // we partial count (K1 c-split)
#define NCS   8                 // A channel groups
#define CPG   32                // channels per A group
#define NPART2 256              // softmax partial pairs
#define NRG   4                 // q row-group split (32 rows each)

// ---------------------------------------------------------------------------
// Algebra: softmax over axis 1 cancels s_theta (constant along that axis) and
// the uniform phi-bias shift -> x, theta_*, phi_b dead. All 1024 output rows
// identical: z = gamma*(g_b + g_w . q).
//   we[cy,t]    = sum_c wp[c]*phi_w[c,cy,t]
//   A[cg,t,pix] = sum_{cy in cg} we[cy,t]*y[cy,pix]   (tap-first: NO halo)
//   sphi[h,w]   = sum_{cg,t} A[cg,t, shifted(h,w)]    (gather done ONCE, K3)
//   p = softmax(sphi);  q[cy,t] = sum_hw p[h-kh+1,w-kw+1]*y[cy,h,w]
// R7 lesson: intra-kernel grid barriers ~120us each on multi-XCD gfx950 ->
//   kernel-boundary sync only.
// R8 lesson: tiny grids (16 blocks) on scattered deps are latency-bound.
// R9 lesson: fusing sphi into the q kernel (64rg x 8cyg) recomputed the
//   A-gather 8x at 2 blocks/CU -> ~80us. Factor sphi into its own 256-block
//   kernel (r5-validated) and use the 1024-block q kernel (r5-validated).
// Harness floor (d_ws re-poison ~43us + input restores) is inside dur_us.
// ---------------------------------------------------------------------------

__device__ __forceinline__ float wave_red_sum(float v) {
    #pragma unroll
    for (int s = 32; s > 0; s >>= 1) v += __shfl_down(v, s, 64);
    return v;
}
__device__ __forceinline__ float wave_red_max(float v) {
    #pragma unroll
    for (int s = 32; s > 0; s >>= 1) v = fmaxf(v, __shfl_down(v, s, 64));
    return v;
}

// K1: we_part[cg][o] = sum_{8 c} wp[c]*phi_w[c,o]   (288 = 32 cg x 9 og)
__global__ __launch_bounds__(256)
void k1_wepart(const float* __restrict__ phi_w,
               const float* __restrict__ concat_w,
               float* __restrict__ we_part) {
    int b = blockIdx.x, t = threadIdx.x;
    int cg = b / 9, og = b - cg * 9;
    int o = og * 256 + t;
    const float* pw = phi_w + o;
    float acc = 0.f;
    #pragma unroll
    for (int j = 0; j < 8; ++j) {
        int c = cg * 8 + j;
        acc = fmaf(concat_w[INTER + c], pw[c * WEN], acc);
    }
    we_part[cg * WEN + o] = acc;
}

// K2: A[cg][k][pix] = sum_{ch in cg} we[.]*y[.]   (512 = 8 cg x 64 pg)
__global__ __launch_bounds__(256)
void k2_taps(const float* __restrict__ y,
             const float* __restrict__ we_part,
             float* __restrict__ A) {
    __shared__ float swe[CPG * KTAPS];
    int t = threadIdx.x;
    int pg = blockIdx.x & 63, cg = blockIdx.x >> 6;

    for (int i = t; i < CPG * KTAPS; i += 256) {
        float s = 0.f;
        #pragma unroll
        for (int p = 0; p < NW1; ++p)
            s += we_part[p * WEN + cg * CPG * KTAPS + i];
        swe[i] = s;
    }
    __syncthreads();

    int pix = pg * 256 + t;
    float acc[KTAPS];
    #pragma unroll
    for (int k = 0; k < KTAPS; ++k) acc[k] = 0.f;
    const float* yp = y + (size_t)cg * CPG * NPIX + pix;
    #pragma unroll 4
    for (int ch = 0; ch < CPG; ++ch) {
        float yv = yp[ch * NPIX];
        const float* wk = swe + ch * KTAPS;     // wave-uniform broadcast
        #pragma unroll
        for (int k = 0; k < KTAPS; ++k)
            acc[k] = fmaf(wk[k], yv, acc[k]);
    }
    #pragma unroll
    for (int k = 0; k < KTAPS; ++k)
        A[(size_t)(cg * KTAPS + k) * NPIX + pix] = acc[k];
}

// K3: sphi[pix] = sum_{cg,k} A[cg][k][shifted]; per-block softmax partials.
// grid 256; block covers 64 pixels x 4 term-groups (2 cg x 9 taps each).
__global__ __launch_bounds__(256)
void k3_sphi(const float* __restrict__ A,
             float* __restrict__ sphi,
             float* __restrict__ partials) {
    __shared__ float sred[256];
    int t = threadIdx.x;
    int tg = t >> 6, pl = t & 63;
    int pix = blockIdx.x * 64 + pl;
    int h = pix >> 7, w = pix & 127;

    int idx[KTAPS]; bool val[KTAPS];
    #pragma unroll
    for (int kh = 0; kh < 3; ++kh)
        #pragma unroll
        for (int kw = 0; kw < 3; ++kw) {
            int hh = h + kh - 1, ww = w + kw - 1;
            int k = kh * 3 + kw;
            val[k] = ((unsigned)hh < HWDIM) & ((unsigned)ww < HWDIM);
            idx[k] = hh * HWDIM + ww;
        }

    float acc = 0.f;
    #pragma unroll
    for (int cc = 0; cc < 2; ++cc) {
        const float* Ab = A + (size_t)(tg * 2 + cc) * KTAPS * NPIX;
        #pragma unroll
        for (int k = 0; k < KTAPS; ++k)
            if (val[k]) acc += Ab[(size_t)k * NPIX + idx[k]];
    }
    sred[t] = acc;
    __syncthreads();

    if (t < 64) {
        float v = sred[t] + sred[t + 64] + sred[t + 128] + sred[t + 192];
        sphi[blockIdx.x * 64 + t] = v;
        float m = wave_red_max(v);
        float M = __shfl(m, 0, 64);
        float e = expf(v - M);
        float s = wave_red_sum(e);
        if (t == 0) {
            partials[2 * blockIdx.x]     = M;
            partials[2 * blockIdx.x + 1] = s;
        }
    }
}

// K4: q_part[rg] over a 32-row slice; merges 256 softmax partials in-block.
// grid 1024 = 4 rg x 256 cy.  (r5-validated body)
__global__ __launch_bounds__(256)
void k4_q(const float* __restrict__ y,
          const float* __restrict__ sphi,
          const float* __restrict__ partials,
          float* __restrict__ q_part) {
    __shared__ float sp[34 * 130];        // padded p tile, 17.7 KB
    __shared__ float s4a[4], s4b[4];
    __shared__ float sq4[4][KTAPS];
    int cy = blockIdx.x & 255;
    int rg = blockIdx.x >> 8;
    int t = threadIdx.x;
    int wid = t >> 6, lane = t & 63;

    // merge 256 partial pairs -> M, invS (thread t owns pair t)
    float m = partials[2 * t], s = partials[2 * t + 1];
    float wm = wave_red_max(m);
    if (lane == 0) s4a[wid] = wm;
    __syncthreads();
    float M = fmaxf(fmaxf(s4a[0], s4a[1]), fmaxf(s4a[2], s4a[3]));
    float sv = s * expf(m - M);
    float wsum = wave_red_sum(sv);
    if (lane == 0) s4b[wid] = wsum;
    __syncthreads();
    float invS = 1.f / (s4b[0] + s4b[1] + s4b[2] + s4b[3]);

    // stage p tile: sp[r][col] = p[rg*32 + r - 1][col - 1], zero-padded
    for (int i = t; i < 34 * 130; i += 256) {
        int r = i / 130, col = i - r * 130;
        int gr = rg * 32 + r - 1, gc = col - 1;
        float v = 0.f;
        if ((unsigned)gr < HWDIM && (unsigned)gc < HWDIM)
            v = expf(sphi[gr * HWDIM + gc] - M) * invS;
        sp[i] = v;
    }
    __syncthreads();

    const float* yc = y + (size_t)cy * NPIX;
    float acc[KTAPS];
    #pragma unroll
    for (int k = 0; k < KTAPS; ++k) acc[k] = 0.f;
    int c = t & 127, vg = t >> 7;

    for (int j = 0; j < 4; ++j) {
        int lr0 = vg * 4 + j * 8;         // local row base (0..28)
        float pv[6][3];
        #pragma unroll
        for (int u = 0; u < 6; ++u)
            #pragma unroll
            for (int v = 0; v < 3; ++v)
                pv[u][v] = sp[(lr0 + u) * 130 + c + v];
        #pragma unroll
        for (int dr = 0; dr < 4; ++dr) {
            float yv = yc[(rg * 32 + lr0 + dr) * HWDIM + c];
            #pragma unroll
            for (int kh = 0; kh < 3; ++kh)
                #pragma unroll
                for (int kw = 0; kw < 3; ++kw)
                    acc[kh * 3 + kw] = fmaf(pv[dr + 2 - kh][2 - kw], yv,
                                            acc[kh * 3 + kw]);
        }
    }

    #pragma unroll
    for (int k = 0; k < KTAPS; ++k) {
        float v = wave_red_sum(acc[k]);
        if (lane == 0) sq4[wid][k] = v;
    }
    __syncthreads();
    if (t < KTAPS)
        q_part[rg * WEN + cy * KTAPS + t] =
            sq4[0][t] + sq4[1][t] + sq4[2][t] + sq4[3][t];
}

// K5: one block per out-channel c: dot(g_w[c,:], sum_rg q_part) + col bcast.
// q_part is already normalized -> plain 4-partial sum. grid 256 x 256.
__global__ __launch_bounds__(256)
void k5_out(const float* __restrict__ g_w,
            const float* __restrict__ g_b,
            const float* __restrict__ gamma,
            const float* __restrict__ q_part,
            float* __restrict__ out, int out_size) {
    __shared__ float s4[4];
    __shared__ float srv;
    int t = threadIdx.x, c = blockIdx.x;
    int wid = t >> 6, lane = t & 63;

    const float* gw = g_w + (size_t)c * WEN;
    float dot = 0.f;
    #pragma unroll
    for (int j = 0; j < 9; ++j) {
        int o = j * 256 + t;
        float v = q_part[o] + q_part[WEN + o] +
                  q_part[2 * WEN + o] + q_part[3 * WEN + o];
        dot = fmaf(gw[o], v, dot);
    }
    float wsum = wave_red_sum(dot);
    if (lane == 0) s4[wid] = wsum;
    __syncthreads();
    if (t == 0)
        srv = gamma[0] * (g_b[c] + s4[0] + s4[1] + s4[2] + s4[3]);
    __syncthreads();
    float rv = srv;

    // column broadcast: out[r*256 + c] for r = t, t+256, t+512, t+768
    #pragma unroll
    for (int i = 0; i < 4; ++i) {
        int gid = (i * 256 + t) * 256 + c;
        if (gid < out_size) out[gid] = rv;
    }
}

extern "C" void kernel_launch(void* const* d_in, const int* in_sizes, int n_in,
                              void* d_out, int out_size, void* d_ws, size_t ws_size,
                              hipStream_t stream) {
    // inputs: x, y, g_w, g_b, phi_w, phi_b, theta_w, theta_b, concat_w, gamma
    const float* y        = (const float*)d_in[1];
    const float* g_w      = (const float*)d_in[2];
    const float* g_b      = (const float*)d_in[3];
    const float* phi_w    = (const float*)d_in[4];
    const float* concat_w = (const float*)d_in[8];
    const float* gamma    = (const float*)d_in[9];
    float* out = (float*)d_out;

    float* ws       = (float*)d_ws;
    float* we_part  = ws;                              // 32*2304   = 73728
    float* A        = we_part + NW1 * WEN;             // 8*9*16384 = 1179648
    float* sphi     = A + (size_t)NCS * KTAPS * NPIX;  // 16384
    float* partials = sphi + NPIX;                     // 512
    float* q_part   = partials + 2 * NPART2;           // 4*2304
    (void)in_sizes; (void)n_in; (void)ws_size;

    hipLaunchKernelGGL(k1_wepart, dim3(288),      dim3(256), 0, stream,
                       phi_w, concat_w, we_part);
    hipLaunchKernelGGL(k2_taps,   dim3(512),      dim3(256), 0, stream,
                       y, we_part, A);
    hipLaunchKernelGGL(k3_sphi,   dim3(NPART2),   dim3(256), 0, stream,
                       A, sphi, partials);
    hipLaunchKernelGGL(k4_q,      dim3(NRG * CY), dim3(256), 0, stream,
                       y, sphi, partials, q_part);
    hipLaunchKernelGGL(k5_out,    dim3(CY),       dim3(256), 0, stream,
                       g_w, g_b, gamma, q_part, out, out_size);
}